// Round 1
// baseline (1021.133 us; speedup 1.0000x reference)
//
#include <hip/hip_runtime.h>

#define D 64

// ---------------------------------------------------------------------------
// K1: per-edge stats: counts per row/col node + segment-sum of edge_label (L=2)
// ---------------------------------------------------------------------------
__global__ __launch_bounds__(256) void k_edge_stats(
    const int* __restrict__ row, const int* __restrict__ col,
    const float* __restrict__ el,          // [E,2]
    float* __restrict__ cnt_row, float* __restrict__ cnt_col,
    float* __restrict__ S_row, float* __restrict__ S_col, int E)
{
    int e = blockIdx.x * 256 + threadIdx.x;
    if (e >= E) return;
    int r = row[e], c = col[e];
    float e0 = el[2 * e], e1 = el[2 * e + 1];
    atomicAdd(&cnt_row[r], 1.0f);
    atomicAdd(&cnt_col[c], 1.0f);
    atomicAdd(&S_row[2 * r],     e0);
    atomicAdd(&S_row[2 * r + 1], e1);
    atomicAdd(&S_col[2 * c],     e0);
    atomicAdd(&S_col[2 * c + 1], e1);
}

// ---------------------------------------------------------------------------
// K2: counts -> reciprocals in place (1/max(cnt,1))
// ---------------------------------------------------------------------------
__global__ __launch_bounds__(256) void k_inv(float* cnt_row, float* cnt_col, int N)
{
    int n = blockIdx.x * 256 + threadIdx.x;
    if (n < N) {
        cnt_row[n] = 1.0f / fmaxf(cnt_row[n], 1.0f);
        cnt_col[n] = 1.0f / fmaxf(cnt_col[n], 1.0f);
    }
}

// ---------------------------------------------------------------------------
// K3: edge scatter of node features. One wave per edge, lane = channel.
//   agg_out[row[e]] += x[col[e]]   ;   agg_inn[col[e]] += x[row[e]]
// ---------------------------------------------------------------------------
__global__ __launch_bounds__(256) void k_scatter(
    const int* __restrict__ row, const int* __restrict__ col,
    const float* __restrict__ x,
    float* __restrict__ agg_out, float* __restrict__ agg_inn, int E)
{
    int e = blockIdx.x * 4 + (threadIdx.x >> 6);
    if (e >= E) return;
    int j = threadIdx.x & 63;
    int r = row[e], c = col[e];
    atomicAdd(&agg_out[r * D + j], x[c * D + j]);
    atomicAdd(&agg_inn[c * D + j], x[r * D + j]);
}

// ---------------------------------------------------------------------------
// K4: per-node combine + dense [N,256]x[256,64] matmul + bias + relu.
// 16 nodes / 256-thread block. h staged in LDS (16KB). W staged in LDS in two
// 128-row chunks (32KB) -> 48KB/block -> 3 blocks/CU. Each thread accumulates
// 4 nodes for its output channel (W read amortized 4x; 2-way bank alias free).
// ---------------------------------------------------------------------------
__global__ __launch_bounds__(256) void k_combine(
    const float* __restrict__ agg_out, const float* __restrict__ agg_inn,
    const float* __restrict__ inv_row, const float* __restrict__ inv_col,
    const float* __restrict__ S_row, const float* __restrict__ S_col,
    const float* __restrict__ tw,     // [2][64]
    const float* __restrict__ W,      // [256][64]
    const float* __restrict__ b,      // [64]
    float* __restrict__ y, int N)
{
    __shared__ float hs[16][256];
    __shared__ float Ws[128 * 64];

    int t    = threadIdx.x;
    int lane = t & 63;
    int wgrp = t >> 6;
    int base = blockIdx.x * 16;

    float tw0 = tw[lane], tw1 = tw[64 + lane];

    // Phase A: assemble h = [out | opinion | inn | inn_opinion] for 16 nodes
    #pragma unroll
    for (int i = 0; i < 4; ++i) {
        int loc = wgrp * 4 + i;
        int n   = base + loc;
        if (n < N) {
            float aggo = agg_out[n * D + lane];
            float aggi = agg_inn[n * D + lane];
            float ir = inv_row[n], ic = inv_col[n];
            float sr0 = S_row[2 * n], sr1 = S_row[2 * n + 1];
            float sc0 = S_col[2 * n], sc1 = S_col[2 * n + 1];
            hs[loc][lane]       = aggo * ir;
            hs[loc][64 + lane]  = (sr0 * tw0 + sr1 * tw1) * ir;
            hs[loc][128 + lane] = aggi * ic;
            hs[loc][192 + lane] = (sc0 * tw0 + sc1 * tw1) * ic;
        } else {
            hs[loc][lane]       = 0.f;
            hs[loc][64 + lane]  = 0.f;
            hs[loc][128 + lane] = 0.f;
            hs[loc][192 + lane] = 0.f;
        }
    }

    float acc[4] = {0.f, 0.f, 0.f, 0.f};

    for (int chunk = 0; chunk < 2; ++chunk) {
        __syncthreads();                       // hs ready (iter 0) / Ws free (iter 1)
        const float* Wsrc = W + chunk * 128 * 64;
        #pragma unroll
        for (int i = 0; i < 32; ++i)
            Ws[i * 256 + t] = Wsrc[i * 256 + t];
        __syncthreads();

        #pragma unroll 4
        for (int j = 0; j < 128; ++j) {
            float w  = Ws[j * 64 + lane];
            int   jj = chunk * 128 + j;
            #pragma unroll
            for (int i = 0; i < 4; ++i)
                acc[i] += hs[wgrp * 4 + i][jj] * w;
        }
    }

    float bias = b[lane];
    #pragma unroll
    for (int i = 0; i < 4; ++i) {
        int n = base + wgrp * 4 + i;
        if (n < N)
            y[n * D + lane] = fmaxf(acc[i] + bias, 0.0f);
    }
}

// ---------------------------------------------------------------------------
extern "C" void kernel_launch(void* const* d_in, const int* in_sizes, int n_in,
                              void* d_out, int out_size, void* d_ws, size_t ws_size,
                              hipStream_t stream)
{
    const float* X   = (const float*)d_in[0];
    const int*   ei  = (const int*)  d_in[1];
    const float* el  = (const float*)d_in[2];
    const float* w1  = (const float*)d_in[3];
    const float* tw1 = (const float*)d_in[4];
    const float* b1  = (const float*)d_in[5];
    const float* w2  = (const float*)d_in[6];
    const float* tw2 = (const float*)d_in[7];
    const float* b2  = (const float*)d_in[8];
    float* out = (float*)d_out;

    int N = in_sizes[0] / D;     // 50000
    int E = in_sizes[1] / 2;     // 800000
    const int* row = ei;
    const int* col = ei + E;

    float* ws      = (float*)d_ws;
    float* cnt_row = ws;                     // N   (becomes inv_row)
    float* cnt_col = ws + (size_t)N;         // N   (becomes inv_col)
    float* S_row   = ws + (size_t)2 * N;     // 2N
    float* S_col   = ws + (size_t)4 * N;     // 2N
    float* agg_out = ws + (size_t)6 * N;     // 64N
    float* agg_inn = ws + (size_t)70 * N;    // 64N
    // h1 lives in d_out (layer-2 combine reads only agg/stat buffers) -> ws = 134N floats

    // ---- shared precompute (layer-independent) ----
    hipMemsetAsync(ws, 0, (size_t)6 * N * sizeof(float), stream);
    k_edge_stats<<<(E + 255) / 256, 256, 0, stream>>>(row, col, el,
                                                      cnt_row, cnt_col, S_row, S_col, E);
    k_inv<<<(N + 255) / 256, 256, 0, stream>>>(cnt_row, cnt_col, N);

    // ---- layer 1 ----
    hipMemsetAsync(agg_out, 0, (size_t)128 * N * sizeof(float), stream);
    k_scatter<<<(E + 3) / 4, 256, 0, stream>>>(row, col, X, agg_out, agg_inn, E);
    k_combine<<<(N + 15) / 16, 256, 0, stream>>>(agg_out, agg_inn, cnt_row, cnt_col,
                                                 S_row, S_col, tw1, w1, b1, out, N);

    // ---- layer 2 (x = h1 stored in d_out) ----
    hipMemsetAsync(agg_out, 0, (size_t)128 * N * sizeof(float), stream);
    k_scatter<<<(E + 3) / 4, 256, 0, stream>>>(row, col, out, agg_out, agg_inn, E);
    k_combine<<<(N + 15) / 16, 256, 0, stream>>>(agg_out, agg_inn, cnt_row, cnt_col,
                                                 S_row, S_col, tw2, w2, b2, out, N);
}

// Round 3
// 680.873 us; speedup vs baseline: 1.4997x; 1.4997x over previous
//
#include <hip/hip_runtime.h>

#define D 64

// ---------------------------------------------------------------------------
// K1: per-edge stats: int degree counts per row/col + segment-sum of labels
// ---------------------------------------------------------------------------
__global__ __launch_bounds__(256) void k_count(
    const int* __restrict__ row, const int* __restrict__ col,
    const float* __restrict__ el,
    int* __restrict__ cnt_row, int* __restrict__ cnt_col,
    float* __restrict__ S_row, float* __restrict__ S_col, int E)
{
    int e = blockIdx.x * 256 + threadIdx.x;
    if (e >= E) return;
    int r = row[e], c = col[e];
    float e0 = el[2 * e], e1 = el[2 * e + 1];
    atomicAdd(&cnt_row[r], 1);
    atomicAdd(&cnt_col[c], 1);
    atomicAdd(&S_row[2 * r],     e0);
    atomicAdd(&S_row[2 * r + 1], e1);
    atomicAdd(&S_col[2 * c],     e0);
    atomicAdd(&S_col[2 * c + 1], e1);
}

// ---------------------------------------------------------------------------
// K2: scan-free CSR region allocation. Wave-level inclusive scan of counts,
// one global-cursor atomic per wave. Region order is arbitrary (per-node
// contiguous), which is all the gather needs. Also emits 1/max(cnt,1).
// ---------------------------------------------------------------------------
__global__ __launch_bounds__(256) void k_alloc(
    const int* __restrict__ cnt, int* __restrict__ off, int* __restrict__ cur,
    float* __restrict__ inv, int* __restrict__ gcur, int N)
{
    int n = blockIdx.x * 256 + threadIdx.x;
    int lane = threadIdx.x & 63;
    int c = (n < N) ? cnt[n] : 0;
    int p = c;
    #pragma unroll
    for (int d = 1; d < 64; d <<= 1) {
        int v = __shfl_up(p, d);
        if (lane >= d) p += v;
    }
    int total = __shfl(p, 63);
    int base = 0;
    if (lane == 63) base = atomicAdd(gcur, total);
    base = __shfl(base, 63);
    int excl = base + p - c;
    if (n < N) {
        off[n] = excl;
        cur[n] = excl;
        inv[n] = 1.0f / fmaxf((float)c, 1.0f);
    }
}

// ---------------------------------------------------------------------------
// K3: bucket fill (order within a node's region is irrelevant for a sum)
// ---------------------------------------------------------------------------
__global__ __launch_bounds__(256) void k_fill(
    const int* __restrict__ row, const int* __restrict__ col,
    int* __restrict__ cur_row, int* __restrict__ cur_col,
    int* __restrict__ nbr_row, int* __restrict__ nbr_col, int E)
{
    int e = blockIdx.x * 256 + threadIdx.x;
    if (e >= E) return;
    int r = row[e], c = col[e];
    nbr_row[atomicAdd(&cur_row[r], 1)] = c;
    nbr_col[atomicAdd(&cur_col[c], 1)] = r;
}

// ---------------------------------------------------------------------------
// K4: fused layer. One block = 16 nodes. Phase A: each wave gathers 4 nodes'
// neighbor sums (lane = channel; idx loads are wave-uniform -> scalar loads;
// feature gathers 256B coalesced) and assembles h[16][256] in LDS.
// Phase B: dense h @ W with W staged in 4x16KB chunks; each thread owns one
// output channel x 4 nodes (W value reused 4x; hs reads broadcast; Ws reads
// 2-way bank alias = free). LDS = 32KB -> 5 blocks/CU -> 20 waves/CU.
// ---------------------------------------------------------------------------
__global__ __launch_bounds__(256) void k_layer(
    const float* __restrict__ x,
    const int* __restrict__ off_row, const int* __restrict__ cnt_row,
    const int* __restrict__ nbr_row,
    const int* __restrict__ off_col, const int* __restrict__ cnt_col,
    const int* __restrict__ nbr_col,
    const float* __restrict__ inv_row, const float* __restrict__ inv_col,
    const float* __restrict__ S_row, const float* __restrict__ S_col,
    const float* __restrict__ tw,    // [2][64]
    const float* __restrict__ W,     // [256][64]
    const float* __restrict__ b,     // [64]
    float* __restrict__ y, int N)
{
    __shared__ float hs[16][256];
    __shared__ float Ws[64 * 64];

    int t    = threadIdx.x;
    int lane = t & 63;
    int w4   = (t >> 6) * 4;
    int base = blockIdx.x * 16;

    float tw0 = tw[lane], tw1 = tw[64 + lane];

    // ---- Phase A: gather + assemble h ----
    #pragma unroll
    for (int i = 0; i < 4; ++i) {
        int loc = w4 + i;
        int n   = base + loc;
        float v0 = 0.f, v1 = 0.f, v2 = 0.f, v3 = 0.f;
        if (n < N) {
            // out = mean over row-bucket of x[col]
            {
                int s = off_row[n], d = cnt_row[n];
                float s0 = 0.f, s1 = 0.f, s2 = 0.f, s3 = 0.f;
                int k = 0;
                for (; k + 4 <= d; k += 4) {
                    int a0 = nbr_row[s + k],     a1 = nbr_row[s + k + 1];
                    int a2 = nbr_row[s + k + 2], a3 = nbr_row[s + k + 3];
                    s0 += x[(size_t)a0 * D + lane];
                    s1 += x[(size_t)a1 * D + lane];
                    s2 += x[(size_t)a2 * D + lane];
                    s3 += x[(size_t)a3 * D + lane];
                }
                for (; k < d; ++k)
                    s0 += x[(size_t)nbr_row[s + k] * D + lane];
                v0 = (s0 + s1) + (s2 + s3);
            }
            // inn = mean over col-bucket of x[row]
            {
                int s = off_col[n], d = cnt_col[n];
                float s0 = 0.f, s1 = 0.f, s2 = 0.f, s3 = 0.f;
                int k = 0;
                for (; k + 4 <= d; k += 4) {
                    int a0 = nbr_col[s + k],     a1 = nbr_col[s + k + 1];
                    int a2 = nbr_col[s + k + 2], a3 = nbr_col[s + k + 3];
                    s0 += x[(size_t)a0 * D + lane];
                    s1 += x[(size_t)a1 * D + lane];
                    s2 += x[(size_t)a2 * D + lane];
                    s3 += x[(size_t)a3 * D + lane];
                }
                for (; k < d; ++k)
                    s0 += x[(size_t)nbr_col[s + k] * D + lane];
                v2 = (s0 + s1) + (s2 + s3);
            }
            float ir = inv_row[n], ic = inv_col[n];
            float sr0 = S_row[2 * n], sr1 = S_row[2 * n + 1];
            float sc0 = S_col[2 * n], sc1 = S_col[2 * n + 1];
            v0 = v0 * ir;
            v1 = (sr0 * tw0 + sr1 * tw1) * ir;
            v2 = v2 * ic;
            v3 = (sc0 * tw0 + sc1 * tw1) * ic;
        }
        hs[loc][lane]       = v0;
        hs[loc][64 + lane]  = v1;
        hs[loc][128 + lane] = v2;
        hs[loc][192 + lane] = v3;
    }

    // ---- Phase B: h @ W (+bias, relu) ----
    float acc[4] = {0.f, 0.f, 0.f, 0.f};
    for (int c = 0; c < 4; ++c) {
        __syncthreads();                 // hs ready (c=0) / Ws drained (c>0)
        const float* Wc = W + c * 64 * D;
        #pragma unroll
        for (int i = 0; i < 16; ++i)
            Ws[i * 256 + t] = Wc[i * 256 + t];
        __syncthreads();

        #pragma unroll 8
        for (int j = 0; j < 64; ++j) {
            float wv = Ws[j * D + lane];
            int   jj = c * 64 + j;
            acc[0] += hs[w4 + 0][jj] * wv;
            acc[1] += hs[w4 + 1][jj] * wv;
            acc[2] += hs[w4 + 2][jj] * wv;
            acc[3] += hs[w4 + 3][jj] * wv;
        }
    }

    float bias = b[lane];
    #pragma unroll
    for (int i = 0; i < 4; ++i) {
        int n = base + w4 + i;
        if (n < N)
            y[(size_t)n * D + lane] = fmaxf(acc[i] + bias, 0.0f);
    }
}

// ---------------------------------------------------------------------------
extern "C" void kernel_launch(void* const* d_in, const int* in_sizes, int n_in,
                              void* d_out, int out_size, void* d_ws, size_t ws_size,
                              hipStream_t stream)
{
    const float* X   = (const float*)d_in[0];
    const int*   ei  = (const int*)  d_in[1];
    const float* el  = (const float*)d_in[2];
    const float* w1  = (const float*)d_in[3];
    const float* tw1 = (const float*)d_in[4];
    const float* b1  = (const float*)d_in[5];
    const float* w2  = (const float*)d_in[6];
    const float* tw2 = (const float*)d_in[7];
    const float* b2  = (const float*)d_in[8];
    float* out = (float*)d_out;

    int N = in_sizes[0] / D;     // 50000
    int E = in_sizes[1] / 2;     // 800000
    const int* row = ei;
    const int* col = ei + E;

    // Workspace layout (all 4B elements), total (76N + 2E + 2)*4 ~= 21.6 MB
    char* ws = (char*)d_ws;
    int*   cnt_row = (int*)ws;                      // N   (zeroed)
    int*   cnt_col = cnt_row + N;                   // N   (zeroed)
    float* S_row   = (float*)(cnt_col + N);         // 2N  (zeroed)
    float* S_col   = S_row + 2 * (size_t)N;         // 2N  (zeroed)
    int*   gcur    = (int*)(S_col + 2 * (size_t)N); // 2   (zeroed)
    int*   off_row = gcur + 2;                      // N
    int*   off_col = off_row + N;                   // N
    int*   cur_row = off_col + N;                   // N
    int*   cur_col = cur_row + N;                   // N
    float* inv_row = (float*)(cur_col + N);         // N
    float* inv_col = inv_row + N;                   // N
    int*   nbr_row = (int*)(inv_col + N);           // E
    int*   nbr_col = nbr_row + E;                   // E
    float* h1      = (float*)(nbr_col + E);         // 64N

    // ---- CSR build + stats (layer-independent, once) ----
    (void)hipMemsetAsync(ws, 0, ((size_t)6 * N + 2) * sizeof(int), stream);
    k_count<<<(E + 255) / 256, 256, 0, stream>>>(row, col, el,
                                                 cnt_row, cnt_col, S_row, S_col, E);
    k_alloc<<<(N + 255) / 256, 256, 0, stream>>>(cnt_row, off_row, cur_row,
                                                 inv_row, gcur + 0, N);
    k_alloc<<<(N + 255) / 256, 256, 0, stream>>>(cnt_col, off_col, cur_col,
                                                 inv_col, gcur + 1, N);
    k_fill<<<(E + 255) / 256, 256, 0, stream>>>(row, col, cur_row, cur_col,
                                                nbr_row, nbr_col, E);

    int nblk = (N + 15) / 16;
    // ---- layer 1: X -> h1 (in ws) ----
    k_layer<<<nblk, 256, 0, stream>>>(X, off_row, cnt_row, nbr_row,
                                      off_col, cnt_col, nbr_col,
                                      inv_row, inv_col, S_row, S_col,
                                      tw1, w1, b1, h1, N);
    // ---- layer 2: h1 -> out ----
    k_layer<<<nblk, 256, 0, stream>>>(h1, off_row, cnt_row, nbr_row,
                                      off_col, cnt_col, nbr_col,
                                      inv_row, inv_col, S_row, S_col,
                                      tw2, w2, b2, out, N);
}

// Round 4
// 560.472 us; speedup vs baseline: 1.8219x; 1.2148x over previous
//
#include <hip/hip_runtime.h>

#define D 64
#define R 4   // atomic replication factor

// ---------------------------------------------------------------------------
// K0: Ttw[which][j] = sum_k tw[a][k] * W[base+k][j]
// which: 0=row/a0, 1=row/a1 (W rows 64..127), 2=col/a0, 3=col/a1 (rows 192..255)
// ---------------------------------------------------------------------------
__global__ __launch_bounds__(256) void k_ttw(
    const float* __restrict__ tw, const float* __restrict__ W,
    float* __restrict__ Ttw)
{
    int t = threadIdx.x;
    int j = t & 63;
    int which = t >> 6;
    int a = which & 1;
    int base = (which < 2) ? 64 : 192;
    float s = 0.f;
    #pragma unroll 8
    for (int k = 0; k < 64; ++k)
        s += tw[a * 64 + k] * W[(base + k) * 64 + j];
    Ttw[which * 64 + j] = s;
}

// ---------------------------------------------------------------------------
// K1: replicated degree counts + one packed f64 label-sum atomic per side.
// pack = (trunc(e0*2^18)*2^26 + trunc(e1*2^18)) * 2^-44  (sums stay exact)
// ---------------------------------------------------------------------------
__global__ __launch_bounds__(256) void k_count(
    const int* __restrict__ row, const int* __restrict__ col,
    const float* __restrict__ el,
    int* __restrict__ cntR, int* __restrict__ cntC,
    double* __restrict__ packR, double* __restrict__ packC, int E, int N)
{
    int e = blockIdx.x * 256 + threadIdx.x;
    if (e >= E) return;
    int r = row[e], c = col[e];
    float2 lab = ((const float2*)el)[e];
    unsigned q0 = (unsigned)(lab.x * 262144.0f);   // 2^18
    unsigned q1 = (unsigned)(lab.y * 262144.0f);
    double p = ((double)q0 * 67108864.0 + (double)q1) * 5.684341886080802e-14; // 2^-44
    int rho = e & (R - 1);
    atomicAdd(&cntR[rho * N + r], 1);
    atomicAdd(&cntC[rho * N + c], 1);
    atomicAdd(&packR[rho * N + r], p);
    atomicAdd(&packC[rho * N + c], p);
}

// ---------------------------------------------------------------------------
// K2: merge replicas -> offsets (wave scan + global cursor), rewrite cnt
// replicas in place as absolute sub-cursors for k_fill, decode packed label
// sums, emit stats[n] = {ir, ic, sr0*ir, sr1*ir, sc0*ic, sc1*ic, degR, degC}
// ---------------------------------------------------------------------------
__global__ __launch_bounds__(256) void k_prep(
    int* __restrict__ cntR, int* __restrict__ cntC,
    const double* __restrict__ packR, const double* __restrict__ packC,
    int* __restrict__ off_row, int* __restrict__ off_col,
    float* __restrict__ stats, int* __restrict__ gcur, int N)
{
    int n = blockIdx.x * 256 + threadIdx.x;
    int lane = threadIdx.x & 63;
    int cr[R], cc[R];
    int tr = 0, tc = 0;
    if (n < N) {
        #pragma unroll
        for (int i = 0; i < R; ++i) {
            cr[i] = cntR[i * N + n]; tr += cr[i];
            cc[i] = cntC[i * N + n]; tc += cc[i];
        }
    } else {
        #pragma unroll
        for (int i = 0; i < R; ++i) { cr[i] = 0; cc[i] = 0; }
    }
    // wave inclusive scans
    int pr = tr, pc = tc;
    #pragma unroll
    for (int d = 1; d < 64; d <<= 1) {
        int vr = __shfl_up(pr, d);
        int vc = __shfl_up(pc, d);
        if (lane >= d) { pr += vr; pc += vc; }
    }
    int totR = __shfl(pr, 63), totC = __shfl(pc, 63);
    int baseR = 0, baseC = 0;
    if (lane == 63) {
        baseR = atomicAdd(&gcur[0], totR);
        baseC = atomicAdd(&gcur[1], totC);
    }
    baseR = __shfl(baseR, 63);
    baseC = __shfl(baseC, 63);
    int offr = baseR + pr - tr;
    int offc = baseC + pc - tc;

    if (n < N) {
        off_row[n] = offr;
        off_col[n] = offc;
        int s = offr;
        #pragma unroll
        for (int i = 0; i < R; ++i) { int v = cr[i]; cntR[i * N + n] = s; s += v; }
        s = offc;
        #pragma unroll
        for (int i = 0; i < R; ++i) { int v = cc[i]; cntC[i * N + n] = s; s += v; }

        double TR = 0.0, TC = 0.0;
        #pragma unroll
        for (int i = 0; i < R; ++i) { TR += packR[i * N + n]; TC += packC[i * N + n]; }
        double TsR = TR * 17592186044416.0;                 // *2^44 (exact int)
        double hiR = floor(TsR * 1.4901161193847656e-08);   // /2^26
        double loR = TsR - hiR * 67108864.0;
        double TsC = TC * 17592186044416.0;
        double hiC = floor(TsC * 1.4901161193847656e-08);
        double loC = TsC - hiC * 67108864.0;

        float ir = 1.0f / fmaxf((float)tr, 1.0f);
        float ic = 1.0f / fmaxf((float)tc, 1.0f);
        stats[(size_t)n * 8 + 0] = ir;
        stats[(size_t)n * 8 + 1] = ic;
        stats[(size_t)n * 8 + 2] = (float)(hiR * 3.814697265625e-06) * ir; // 2^-18
        stats[(size_t)n * 8 + 3] = (float)(loR * 3.814697265625e-06) * ir;
        stats[(size_t)n * 8 + 4] = (float)(hiC * 3.814697265625e-06) * ic;
        stats[(size_t)n * 8 + 5] = (float)(loC * 3.814697265625e-06) * ic;
        stats[(size_t)n * 8 + 6] = (float)tr;
        stats[(size_t)n * 8 + 7] = (float)tc;
    }
}

// ---------------------------------------------------------------------------
// K3: bucket fill via replicated sub-cursors (contention /R, no gaps)
// ---------------------------------------------------------------------------
__global__ __launch_bounds__(256) void k_fill(
    const int* __restrict__ row, const int* __restrict__ col,
    int* __restrict__ curR, int* __restrict__ curC,
    int* __restrict__ nbr_row, int* __restrict__ nbr_col, int E, int N)
{
    int e = blockIdx.x * 256 + threadIdx.x;
    if (e >= E) return;
    int r = row[e], c = col[e];
    int rho = e & (R - 1);
    nbr_row[atomicAdd(&curR[rho * N + r], 1)] = c;
    nbr_col[atomicAdd(&curC[rho * N + c], 1)] = r;
}

// ---------------------------------------------------------------------------
// K4: fused layer, h reduced to 128 dims ([out|inn]); opinion terms folded as
// rank-2 epilogue via Ttw. 16 nodes/block; hs 8KB + Ws 32KB = 40KB -> 4 blk/CU.
// ---------------------------------------------------------------------------
__global__ __launch_bounds__(256) void k_layer(
    const float* __restrict__ x,
    const int* __restrict__ off_row, const int* __restrict__ off_col,
    const int* __restrict__ nbr_row, const int* __restrict__ nbr_col,
    const float* __restrict__ stats,
    const float* __restrict__ Ttw,   // [4][64]
    const float* __restrict__ W,     // [256][64]
    const float* __restrict__ b,     // [64]
    float* __restrict__ y, int N)
{
    __shared__ float hs[16][128];
    __shared__ float Ws[128 * 64];

    int t    = threadIdx.x;
    int lane = t & 63;
    int w4   = (t >> 6) * 4;
    int base = blockIdx.x * 16;

    float sf[4][4];   // per node: {sr0*ir, sr1*ir, sc0*ic, sc1*ic}

    // ---- Phase A: gather + assemble h = [out | inn] ----
    #pragma unroll
    for (int i = 0; i < 4; ++i) {
        int loc = w4 + i;
        int n   = base + loc;
        float v0 = 0.f, v2 = 0.f;
        sf[i][0] = sf[i][1] = sf[i][2] = sf[i][3] = 0.f;
        if (n < N) {
            const float* sN = stats + (size_t)n * 8;
            float ir = sN[0], ic = sN[1];
            sf[i][0] = sN[2]; sf[i][1] = sN[3];
            sf[i][2] = sN[4]; sf[i][3] = sN[5];
            int dR = (int)sN[6], dC = (int)sN[7];
            {
                int s = off_row[n];
                float s0 = 0.f, s1 = 0.f, s2 = 0.f, s3 = 0.f;
                int k = 0;
                for (; k + 4 <= dR; k += 4) {
                    int a0 = nbr_row[s + k],     a1 = nbr_row[s + k + 1];
                    int a2 = nbr_row[s + k + 2], a3 = nbr_row[s + k + 3];
                    s0 += x[(size_t)a0 * D + lane];
                    s1 += x[(size_t)a1 * D + lane];
                    s2 += x[(size_t)a2 * D + lane];
                    s3 += x[(size_t)a3 * D + lane];
                }
                for (; k < dR; ++k)
                    s0 += x[(size_t)nbr_row[s + k] * D + lane];
                v0 = ((s0 + s1) + (s2 + s3)) * ir;
            }
            {
                int s = off_col[n];
                float s0 = 0.f, s1 = 0.f, s2 = 0.f, s3 = 0.f;
                int k = 0;
                for (; k + 4 <= dC; k += 4) {
                    int a0 = nbr_col[s + k],     a1 = nbr_col[s + k + 1];
                    int a2 = nbr_col[s + k + 2], a3 = nbr_col[s + k + 3];
                    s0 += x[(size_t)a0 * D + lane];
                    s1 += x[(size_t)a1 * D + lane];
                    s2 += x[(size_t)a2 * D + lane];
                    s3 += x[(size_t)a3 * D + lane];
                }
                for (; k < dC; ++k)
                    s0 += x[(size_t)nbr_col[s + k] * D + lane];
                v2 = ((s0 + s1) + (s2 + s3)) * ic;
            }
        }
        hs[loc][lane]      = v0;
        hs[loc][64 + lane] = v2;
    }

    __syncthreads();
    // stage W rows 0..63 and 128..191 as Ws[0..127]
    #pragma unroll
    for (int i = 0; i < 32; ++i) {
        int L = i * 256 + t;
        Ws[L] = W[L + ((L < 4096) ? 0 : 4096)];
    }
    __syncthreads();

    float acc[4] = {0.f, 0.f, 0.f, 0.f};
    #pragma unroll 8
    for (int j = 0; j < 128; ++j) {
        float wv = Ws[j * 64 + lane];
        acc[0] += hs[w4 + 0][j] * wv;
        acc[1] += hs[w4 + 1][j] * wv;
        acc[2] += hs[w4 + 2][j] * wv;
        acc[3] += hs[w4 + 3][j] * wv;
    }

    // rank-2 opinion epilogue + bias + relu
    float tR0 = Ttw[lane], tR1 = Ttw[64 + lane];
    float tC0 = Ttw[128 + lane], tC1 = Ttw[192 + lane];
    float bias = b[lane];
    #pragma unroll
    for (int i = 0; i < 4; ++i) {
        int n = base + w4 + i;
        if (n < N) {
            float v = acc[i] + sf[i][0] * tR0 + sf[i][1] * tR1
                             + sf[i][2] * tC0 + sf[i][3] * tC1 + bias;
            y[(size_t)n * D + lane] = fmaxf(v, 0.0f);
        }
    }
}

// ---------------------------------------------------------------------------
extern "C" void kernel_launch(void* const* d_in, const int* in_sizes, int n_in,
                              void* d_out, int out_size, void* d_ws, size_t ws_size,
                              hipStream_t stream)
{
    const float* X   = (const float*)d_in[0];
    const int*   ei  = (const int*)  d_in[1];
    const float* el  = (const float*)d_in[2];
    const float* w1  = (const float*)d_in[3];
    const float* tw1 = (const float*)d_in[4];
    const float* b1  = (const float*)d_in[5];
    const float* w2  = (const float*)d_in[6];
    const float* tw2 = (const float*)d_in[7];
    const float* b2  = (const float*)d_in[8];
    float* out = (float*)d_out;

    int N = in_sizes[0] / D;     // 50000
    int E = in_sizes[1] / 2;     // 800000
    const int* row = ei;
    const int* col = ei + E;

    // Workspace layout, total ~26.0 MB (proven budget: 26.8 MB in round 1)
    double* packR  = (double*)d_ws;                   // R*N doubles (zeroed)
    double* packC  = packR + (size_t)R * N;           // R*N doubles (zeroed)
    int*   cntR    = (int*)(packC + (size_t)R * N);   // R*N (zeroed; -> sub-cursors)
    int*   cntC    = cntR + (size_t)R * N;            // R*N (zeroed; -> sub-cursors)
    int*   gcur    = cntC + (size_t)R * N;            // 2   (zeroed)
    int*   off_row = gcur + 2;                        // N
    int*   off_col = off_row + N;                     // N
    float* stats   = (float*)(off_col + N);           // 8N
    float* Ttw1    = stats + (size_t)8 * N;           // 256
    float* Ttw2    = Ttw1 + 256;                      // 256
    int*   nbr_row = (int*)(Ttw2 + 256);              // E
    int*   nbr_col = nbr_row + E;                     // E
    float* h1      = (float*)(nbr_col + E);           // 64N

    size_t zero_bytes = (size_t)2 * R * N * 8 + ((size_t)2 * R * N + 2) * 4;
    (void)hipMemsetAsync(d_ws, 0, zero_bytes, stream);

    k_ttw<<<1, 256, 0, stream>>>(tw1, w1, Ttw1);
    k_ttw<<<1, 256, 0, stream>>>(tw2, w2, Ttw2);

    int EB = (E + 255) / 256;
    int NB = (N + 255) / 256;
    int LB = (N + 15) / 16;

    k_count<<<EB, 256, 0, stream>>>(row, col, el, cntR, cntC, packR, packC, E, N);
    k_prep<<<NB, 256, 0, stream>>>(cntR, cntC, packR, packC,
                                   off_row, off_col, stats, gcur, N);
    k_fill<<<EB, 256, 0, stream>>>(row, col, cntR, cntC, nbr_row, nbr_col, E, N);

    k_layer<<<LB, 256, 0, stream>>>(X, off_row, off_col, nbr_row, nbr_col,
                                    stats, Ttw1, w1, b1, h1, N);
    k_layer<<<LB, 256, 0, stream>>>(h1, off_row, off_col, nbr_row, nbr_col,
                                    stats, Ttw2, w2, b2, out, N);
}

// Round 5
// 397.380 us; speedup vs baseline: 2.5697x; 1.4104x over previous
//
#include <hip/hip_runtime.h>

#define D 64
#define R 4   // replication factor for atomic de-contention

typedef unsigned long long u64;

// ---------------------------------------------------------------------------
// K0: Ttw[which][j] = sum_k tw[a][k] * W[base+k][j]  for both layers
// which: 0=row/a0, 1=row/a1 (W rows 64..127), 2=col/a0, 3=col/a1 (rows 192..255)
// block 0 -> layer 1, block 1 -> layer 2
// ---------------------------------------------------------------------------
__global__ __launch_bounds__(256) void k_ttw(
    const float* __restrict__ tw1, const float* __restrict__ W1, float* __restrict__ T1,
    const float* __restrict__ tw2, const float* __restrict__ W2, float* __restrict__ T2)
{
    const float* tw = blockIdx.x ? tw2 : tw1;
    const float* W  = blockIdx.x ? W2  : W1;
    float*       T  = blockIdx.x ? T2  : T1;
    int t = threadIdx.x;
    int j = t & 63;
    int which = t >> 6;
    int a = which & 1;
    int base = (which < 2) ? 64 : 192;
    float s = 0.f;
    #pragma unroll 8
    for (int k = 0; k < 64; ++k)
        s += tw[a * 64 + k] * W[(base + k) * 64 + j];
    T[which * 64 + j] = s;
}

// ---------------------------------------------------------------------------
// K1: ONE u64 atomic per edge per side: fields [cnt:10 | q0:27 | q1:27],
// labels quantized at 2^16 (err 1.5e-5). Field sums can't overflow
// (deg << 1024, q-sum < 2^26 < 2^27). Replicated x4 to cut contention.
// ---------------------------------------------------------------------------
__global__ __launch_bounds__(256) void k_count(
    const int* __restrict__ row, const int* __restrict__ col,
    const float* __restrict__ el,
    u64* __restrict__ packR, u64* __restrict__ packC, int E, int N)
{
    int e = blockIdx.x * 256 + threadIdx.x;
    if (e >= E) return;
    int r = row[e], c = col[e];
    float2 lab = ((const float2*)el)[e];
    u64 q0 = (u64)(unsigned)(lab.x * 65536.0f);
    u64 q1 = (u64)(unsigned)(lab.y * 65536.0f);
    u64 p = (1ULL << 54) | (q0 << 27) | q1;
    int rho = e & (R - 1);
    atomicAdd(&packR[rho * N + r], p);
    atomicAdd(&packC[rho * N + c], p);
}

// ---------------------------------------------------------------------------
// K2: decode replicas -> degrees; wave scan + global cursor -> offsets;
// write absolute per-replica sub-cursors for k_fill; decode label sums;
// emit stats[n] = {ir, ic, sr0*ir, sr1*ir, sc0*ic, sc1*ic, degR, degC}
// ---------------------------------------------------------------------------
__global__ __launch_bounds__(256) void k_prep(
    const u64* __restrict__ packR, const u64* __restrict__ packC,
    int* __restrict__ curR, int* __restrict__ curC,
    int* __restrict__ off_row, int* __restrict__ off_col,
    float* __restrict__ stats, int* __restrict__ gcur, int N)
{
    int n = blockIdx.x * 256 + threadIdx.x;
    int lane = threadIdx.x & 63;
    int cr[R], cc[R];
    u64 TR = 0, TC = 0;
    int tr = 0, tc = 0;
    if (n < N) {
        #pragma unroll
        for (int i = 0; i < R; ++i) {
            u64 pR = packR[(size_t)i * N + n];
            u64 pC = packC[(size_t)i * N + n];
            cr[i] = (int)(pR >> 54); tr += cr[i]; TR += pR;
            cc[i] = (int)(pC >> 54); tc += cc[i]; TC += pC;
        }
    } else {
        #pragma unroll
        for (int i = 0; i < R; ++i) { cr[i] = 0; cc[i] = 0; }
    }
    // wave inclusive scans of tr, tc
    int pr = tr, pc = tc;
    #pragma unroll
    for (int d = 1; d < 64; d <<= 1) {
        int vr = __shfl_up(pr, d);
        int vc = __shfl_up(pc, d);
        if (lane >= d) { pr += vr; pc += vc; }
    }
    int totR = __shfl(pr, 63), totC = __shfl(pc, 63);
    int baseR = 0, baseC = 0;
    if (lane == 63) {
        baseR = atomicAdd(&gcur[0], totR);
        baseC = atomicAdd(&gcur[1], totC);
    }
    baseR = __shfl(baseR, 63);
    baseC = __shfl(baseC, 63);
    int offr = baseR + pr - tr;
    int offc = baseC + pc - tc;

    if (n < N) {
        off_row[n] = offr;
        off_col[n] = offc;
        int s = offr;
        #pragma unroll
        for (int i = 0; i < R; ++i) { curR[(size_t)i * N + n] = s; s += cr[i]; }
        s = offc;
        #pragma unroll
        for (int i = 0; i < R; ++i) { curC[(size_t)i * N + n] = s; s += cc[i]; }

        const u64 M27 = (1ULL << 27) - 1;
        const float qs = 1.0f / 65536.0f;
        float sr0 = (float)((TR >> 27) & M27) * qs;
        float sr1 = (float)(TR & M27) * qs;
        float sc0 = (float)((TC >> 27) & M27) * qs;
        float sc1 = (float)(TC & M27) * qs;

        float ir = 1.0f / fmaxf((float)tr, 1.0f);
        float ic = 1.0f / fmaxf((float)tc, 1.0f);
        float* sN = stats + (size_t)n * 8;
        sN[0] = ir;        sN[1] = ic;
        sN[2] = sr0 * ir;  sN[3] = sr1 * ir;
        sN[4] = sc0 * ic;  sN[5] = sc1 * ic;
        sN[6] = (float)tr; sN[7] = (float)tc;
    }
}

// ---------------------------------------------------------------------------
// K3: bucket fill via replicated sub-cursors (contention /R, no gaps)
// ---------------------------------------------------------------------------
__global__ __launch_bounds__(256) void k_fill(
    const int* __restrict__ row, const int* __restrict__ col,
    int* __restrict__ curR, int* __restrict__ curC,
    int* __restrict__ nbr_row, int* __restrict__ nbr_col, int E, int N)
{
    int e = blockIdx.x * 256 + threadIdx.x;
    if (e >= E) return;
    int r = row[e], c = col[e];
    int rho = e & (R - 1);
    nbr_row[atomicAdd(&curR[(size_t)rho * N + r], 1)] = c;
    nbr_col[atomicAdd(&curC[(size_t)rho * N + c], 1)] = r;
}

// ---------------------------------------------------------------------------
// K4: fused layer. 512 threads (8 waves), 16 nodes/block, 2 nodes/wave.
// Gather: lane=(grp,c4); one float4 instruction fetches 4 neighbor rows
// (1KB/wave-instr); cross-group shfl_xor(16,32) reduce. Index loads are 16B
// coalesced. LDS = hs 8KB + Ws 32KB = 40KB -> 4 blocks x 8 waves = 32 waves/CU.
// MLP: lane=out channel, 2 nodes/wave; rank-2 opinion epilogue via Ttw.
// ---------------------------------------------------------------------------
__global__ __launch_bounds__(512) void k_layer(
    const float* __restrict__ x,
    const int* __restrict__ off_row, const int* __restrict__ off_col,
    const int* __restrict__ nbr_row, const int* __restrict__ nbr_col,
    const float* __restrict__ stats,
    const float* __restrict__ Ttw,   // [4][64]
    const float* __restrict__ W,     // [256][64]
    const float* __restrict__ b,     // [64]
    float* __restrict__ y, int N)
{
    __shared__ float4 hs4[16][32];
    __shared__ float  Ws[128 * 64];

    const float4* x4 = (const float4*)x;

    int t    = threadIdx.x;
    int lane = t & 63;
    int wv   = t >> 6;        // 0..7
    int c4   = lane & 15;
    int grp  = lane >> 4;     // 0..3
    int base = blockIdx.x * 16;

    float sf[2][4];

    // ---- Phase A: gather (float4, 4 neighbors per wave-instruction) ----
    #pragma unroll
    for (int i = 0; i < 2; ++i) {
        int loc = wv * 2 + i;
        int n   = base + loc;
        float4 accR = make_float4(0.f, 0.f, 0.f, 0.f);
        float4 accC = make_float4(0.f, 0.f, 0.f, 0.f);
        float ir = 0.f, ic = 0.f;
        sf[i][0] = sf[i][1] = sf[i][2] = sf[i][3] = 0.f;
        if (n < N) {
            const float4* st = (const float4*)(stats + (size_t)n * 8);
            float4 sA = st[0];   // ir, ic, sr0', sr1'
            float4 sB = st[1];   // sc0', sc1', degR, degC
            ir = sA.x; ic = sA.y;
            sf[i][0] = sA.z; sf[i][1] = sA.w;
            sf[i][2] = sB.x; sf[i][3] = sB.y;
            int dR = (int)sB.z, dC = (int)sB.w;
            int sR = off_row[n], sC = off_col[n];
            for (int k = 0; k < dR; k += 4) {
                int kk = k + grp;
                bool p = kk < dR;
                int a = nbr_row[sR + (p ? kk : 0)];
                float4 v = x4[(size_t)a * 16 + c4];
                if (p) { accR.x += v.x; accR.y += v.y; accR.z += v.z; accR.w += v.w; }
            }
            for (int k = 0; k < dC; k += 4) {
                int kk = k + grp;
                bool p = kk < dC;
                int a = nbr_col[sC + (p ? kk : 0)];
                float4 v = x4[(size_t)a * 16 + c4];
                if (p) { accC.x += v.x; accC.y += v.y; accC.z += v.z; accC.w += v.w; }
            }
        }
        // cross-group reduce: lanes {c4, c4+16, c4+32, c4+48} -> full sum
        #pragma unroll
        for (int o = 16; o < 64; o <<= 1) {
            accR.x += __shfl_xor(accR.x, o); accR.y += __shfl_xor(accR.y, o);
            accR.z += __shfl_xor(accR.z, o); accR.w += __shfl_xor(accR.w, o);
            accC.x += __shfl_xor(accC.x, o); accC.y += __shfl_xor(accC.y, o);
            accC.z += __shfl_xor(accC.z, o); accC.w += __shfl_xor(accC.w, o);
        }
        if (grp == 0) {
            hs4[loc][c4]      = make_float4(accR.x * ir, accR.y * ir, accR.z * ir, accR.w * ir);
            hs4[loc][16 + c4] = make_float4(accC.x * ic, accC.y * ic, accC.z * ic, accC.w * ic);
        }
    }

    // ---- stage W (rows 0..63 and 128..191) ----
    __syncthreads();
    #pragma unroll
    for (int i = 0; i < 16; ++i) {
        int L = i * 512 + t;
        Ws[L] = W[L + ((L < 4096) ? 0 : 4096)];
    }
    __syncthreads();

    // ---- Phase B: h @ W ----
    const float* hsf = (const float*)hs4;
    int r0 = (wv * 2) * 128, r1 = r0 + 128;
    float a0 = 0.f, a1 = 0.f;
    #pragma unroll 8
    for (int j = 0; j < 128; ++j) {
        float wj = Ws[j * 64 + lane];
        a0 += hsf[r0 + j] * wj;
        a1 += hsf[r1 + j] * wj;
    }

    // ---- rank-2 opinion epilogue + bias + relu ----
    float tR0 = Ttw[lane],       tR1 = Ttw[64 + lane];
    float tC0 = Ttw[128 + lane], tC1 = Ttw[192 + lane];
    float bias = b[lane];
    float vv[2] = {a0, a1};
    #pragma unroll
    for (int i = 0; i < 2; ++i) {
        int n = base + wv * 2 + i;
        if (n < N) {
            float v = vv[i] + sf[i][0] * tR0 + sf[i][1] * tR1
                            + sf[i][2] * tC0 + sf[i][3] * tC1 + bias;
            y[(size_t)n * D + lane] = fmaxf(v, 0.0f);
        }
    }
}

// ---------------------------------------------------------------------------
extern "C" void kernel_launch(void* const* d_in, const int* in_sizes, int n_in,
                              void* d_out, int out_size, void* d_ws, size_t ws_size,
                              hipStream_t stream)
{
    const float* X   = (const float*)d_in[0];
    const int*   ei  = (const int*)  d_in[1];
    const float* el  = (const float*)d_in[2];
    const float* w1  = (const float*)d_in[3];
    const float* tw1 = (const float*)d_in[4];
    const float* b1  = (const float*)d_in[5];
    const float* w2  = (const float*)d_in[6];
    const float* tw2 = (const float*)d_in[7];
    const float* b2  = (const float*)d_in[8];
    float* out = (float*)d_out;

    int N = in_sizes[0] / D;     // 50000
    int E = in_sizes[1] / 2;     // 800000
    const int* row = ei;
    const int* col = ei + E;

    // Workspace layout (~26.0 MB)
    u64*   packR   = (u64*)d_ws;                      // R*N u64 (zeroed)
    u64*   packC   = packR + (size_t)R * N;           // R*N u64 (zeroed)
    int*   gcur    = (int*)(packC + (size_t)R * N);   // 4 ints (zeroed; 16B pad)
    int*   curR    = gcur + 4;                        // R*N
    int*   curC    = curR + (size_t)R * N;            // R*N
    int*   off_row = curC + (size_t)R * N;            // N
    int*   off_col = off_row + N;                     // N
    float* stats   = (float*)(off_col + N);           // 8N (16B-aligned)
    float* Ttw1    = stats + (size_t)8 * N;           // 256
    float* Ttw2    = Ttw1 + 256;                      // 256
    int*   nbr_row = (int*)(Ttw2 + 256);              // E
    int*   nbr_col = nbr_row + E;                     // E
    float* h1      = (float*)(nbr_col + E);           // 64N (16B-aligned)

    (void)hipMemsetAsync(d_ws, 0, (size_t)2 * R * N * sizeof(u64) + 16, stream);

    k_ttw<<<2, 256, 0, stream>>>(tw1, w1, Ttw1, tw2, w2, Ttw2);

    int EB = (E + 255) / 256;
    int NB = (N + 255) / 256;
    int LB = (N + 15) / 16;

    k_count<<<EB, 256, 0, stream>>>(row, col, el, packR, packC, E, N);
    k_prep<<<NB, 256, 0, stream>>>(packR, packC, curR, curC,
                                   off_row, off_col, stats, gcur, N);
    k_fill<<<EB, 256, 0, stream>>>(row, col, curR, curC, nbr_row, nbr_col, E, N);

    k_layer<<<LB, 512, 0, stream>>>(X, off_row, off_col, nbr_row, nbr_col,
                                    stats, Ttw1, w1, b1, h1, N);
    k_layer<<<LB, 512, 0, stream>>>(h1, off_row, off_col, nbr_row, nbr_col,
                                    stats, Ttw2, w2, b2, out, N);
}